// Round 4
// baseline (4561.812 us; speedup 1.0000x reference)
//
#include <hip/hip_runtime.h>
#include <hip/hip_cooperative_groups.h>

typedef __attribute__((ext_vector_type(8))) short short8;   // 8 bf16 (4 VGPRs)
typedef __attribute__((ext_vector_type(4))) float f32x4;
typedef __attribute__((ext_vector_type(4))) float floatx4;
typedef __attribute__((ext_vector_type(4))) unsigned int uintx4;
typedef __attribute__((ext_vector_type(2))) unsigned int uintx2;
typedef __attribute__((ext_vector_type(4))) unsigned int u32x4;

#define MFMA16(a, b, c) __builtin_amdgcn_mfma_f32_16x16x32_bf16(a, b, c, 0, 0, 0)

// B=64, S=512, V=32000, D=1024, H=1024, C=1000
#define SB_ROWS 32768   // S*B, row m = s*64 + b

#define AT_LOAD_U32(p)  __hip_atomic_load((p), __ATOMIC_RELAXED, __HIP_MEMORY_SCOPE_AGENT)
#define AT_STORE_U32(p, v) __hip_atomic_store((p), (v), __ATOMIC_RELAXED, __HIP_MEMORY_SCOPE_AGENT)

__device__ __forceinline__ unsigned short f2bf(float f) {
  unsigned u = __float_as_uint(f);
  u += 0x7fffu + ((u >> 16) & 1u);          // RNE
  return (unsigned short)(u >> 16);
}
__device__ __forceinline__ float bf2f(short s) {
  return __uint_as_float(((unsigned)(unsigned short)s) << 16);
}
__device__ __forceinline__ float sigmoidf_(float x) {
  return 1.0f / (1.0f + __expf(-x));
}
__device__ __forceinline__ void gld_lds16(const void* g, void* l) {
  __builtin_amdgcn_global_load_lds(
      (const __attribute__((address_space(1))) unsigned int*)g,
      (__attribute__((address_space(3))) unsigned int*)l, 16, 0, 0);
}
__device__ __forceinline__ void gld_lds4(const void* g, void* l) {
  __builtin_amdgcn_global_load_lds(
      (const __attribute__((address_space(1))) unsigned int*)g,
      (__attribute__((address_space(3))) unsigned int*)l, 4, 0, 0);
}

// ---------------- f32 -> bf16 cast (n multiple of 4) ----------------
__global__ __launch_bounds__(256) void cast_bf16_k(const float* __restrict__ src,
                                                   short* __restrict__ dst, int n) {
  int i = (blockIdx.x * 256 + threadIdx.x) * 4;
  if (i >= n) return;
  floatx4 v = *(const floatx4*)(src + i);
  unsigned int lo = f2bf(v.x) | ((unsigned)f2bf(v.y) << 16);
  unsigned int hi = f2bf(v.z) | ((unsigned)f2bf(v.w) << 16);
  uintx2 o; o.x = lo; o.y = hi;
  *(uintx2*)(dst + i) = o;
}

// ---------------- embedding gather: xe16[s*64+b][d] = bf16(emb[x[b][s]][d]) ----------------
__global__ __launch_bounds__(128) void embed_gather(const int* __restrict__ x,
                                                    const float* __restrict__ emb,
                                                    short* __restrict__ xe16) {
  const int m = blockIdx.x;            // s*64 + b
  const int s = m >> 6, b = m & 63;
  const int idx = x[b * 512 + s];
  const int d0 = threadIdx.x * 8;
  const float* src = emb + (size_t)idx * 1024 + d0;
  floatx4 a = *(const floatx4*)src;
  floatx4 c = *(const floatx4*)(src + 4);
  uintx4 o;
  o.x = f2bf(a.x) | ((unsigned)f2bf(a.y) << 16);
  o.y = f2bf(a.z) | ((unsigned)f2bf(a.w) << 16);
  o.z = f2bf(c.x) | ((unsigned)f2bf(c.y) << 16);
  o.w = f2bf(c.z) | ((unsigned)f2bf(c.w) << 16);
  *(uintx4*)(xe16 + (size_t)m * 1024 + d0) = o;
}

// ---------------- batched projections: xfi[m][0:1024]=xe@Wf^T+bf, [1024:2048]=xe@Wi^T+bi ----
__global__ __launch_bounds__(256, 2) void gemm_xfi(const short* __restrict__ A,
                                                   const short* __restrict__ Wf,
                                                   const short* __restrict__ Wi,
                                                   const float* __restrict__ bfp,
                                                   const float* __restrict__ bip,
                                                   float* __restrict__ Cout) {
  __shared__ __align__(16) short As[128 * 64];
  __shared__ __align__(16) short Bs[128 * 64];
  const int tid = threadIdx.x;
  const int wave = tid >> 6, lane = tid & 63;
  const int quad = lane >> 4, l15 = lane & 15;
  const int nt = blockIdx.x & 15;
  const long m0 = (long)(blockIdx.x >> 4) * 128;
  const int n0 = nt * 128;
  const short* Bm = (n0 < 1024) ? Wf : Wi;
  const int nb = (n0 < 1024) ? n0 : n0 - 1024;
  const int wm = (wave >> 1) * 64, wn = (wave & 1) * 64;

  f32x4 acc[4][4] = {};
  const int cb = wave * 4;

  for (int k0 = 0; k0 < 1024; k0 += 64) {
    __syncthreads();
#pragma unroll
    for (int q = 0; q < 4; ++q) {
      int Cc = (cb + q) * 64 + lane;
      int row = Cc >> 3, slot = Cc & 7;
      int gk = k0 + ((slot ^ (row & 7)) << 3);
      gld_lds16(A + (m0 + row) * 1024 + gk, As + (size_t)(cb + q) * 512);
      gld_lds16(Bm + (long)(nb + row) * 1024 + gk, Bs + (size_t)(cb + q) * 512);
    }
    __syncthreads();
#pragma unroll
    for (int ks = 0; ks < 2; ++ks) {
      short8 av[4], bv[4];
      const int slin = ks * 4 + quad;
#pragma unroll
      for (int i = 0; i < 4; ++i) {
        int row = wm + i * 16 + l15;
        int slot = slin ^ (row & 7);
        av[i] = *(const short8*)&As[row * 64 + slot * 8];
      }
#pragma unroll
      for (int j = 0; j < 4; ++j) {
        int col = wn + j * 16 + l15;
        int slot = slin ^ (col & 7);
        bv[j] = *(const short8*)&Bs[col * 64 + slot * 8];
      }
#pragma unroll
      for (int i = 0; i < 4; ++i)
#pragma unroll
        for (int j = 0; j < 4; ++j) acc[i][j] = MFMA16(av[i], bv[j], acc[i][j]);
    }
  }
#pragma unroll
  for (int j = 0; j < 4; ++j) {
    int ng = n0 + wn + j * 16 + l15;
    float bias = (ng < 1024) ? bfp[ng] : bip[ng - 1024];
#pragma unroll
    for (int i = 0; i < 4; ++i)
#pragma unroll
      for (int r = 0; r < 4; ++r) {
        long m = m0 + wm + i * 16 + quad * 4 + r;
        Cout[m * 2048 + ng] = acc[i][j][r] + bias;
      }
  }
}

// ---------------- cooperative recurrence: 512 steps, 32 blocks x 512 thr ----------------
// R8: 32 blocks x 32 cols (halves LLC read redundancy: 4MB/step), Uf fragments held
// permanently in registers (bF[2][16], 128 VGPR, loaded once from global — no LDS reads
// for gate f), Ui staged swizzled in LDS (2 ds_read_b128 per k-step as before).
// xf/xi prefetch goes to LDS via global_load_lds (frees VGPRs; drained naturally by the
// next poll's vmcnt wait, a full store-ack + barrier later). h-store ack uses a counted
// s_waitcnt vmcnt(24) (4 stores oldest, 24 pf younger; order pinned by sched_barrier(0)),
// and barrier#2 is a RAW s_barrier so the pf stays in flight across it.
// Waves: w3 = wave&3 (16-row group), kh = wave>>2 (k-half). kh1 -> Pr partials in LDS
// (single-buffered: safe between barrier#1(t) and barrier#2(t)); kh0 -> gating/stores/pf.
// Cross-block safety: block writes buffer rp^1 at t only after poll(t) (all flags >= t),
// and flag j >= t implies block j finished reading buffer rp^1 at t-1. Flags monotonic.
__global__ __launch_bounds__(512, 2) void ran_scan(const float* __restrict__ xfi,
                                                   const short* __restrict__ xe16,
                                                   const short* __restrict__ Uf,
                                                   const short* __restrict__ Ui,
                                                   short* __restrict__ h16,
                                                   unsigned* __restrict__ flg) {
  __shared__ __align__(16) short Ui_s[32 * 1024];    // 64 KB swizzled Ui rows c0..c0+31
  __shared__ float Pr[4][2][2][4][64];               // 16 KB partials [w3][g][ct][r][lane]
  __shared__ float pfL[2][4][2][2][4][64];           // 32 KB pf [par][w3][g][ct][r][lane]
  const int tid = threadIdx.x;
  const int wave = tid >> 6, lane = tid & 63;
  const int w3 = wave & 3, kh = wave >> 2;           // row-group, k-half
  const int quad = lane >> 4, l15 = lane & 15;
  const int c0 = blockIdx.x * 32;
  const int rw = w3 * 16;

  // stage Ui rows c0..c0+31, 16B-chunk XOR swizzle (row&7)
  for (int it = 0; it < 8; ++it) {
    int Cc = it * 512 + tid;         // 0..4095
    int row = Cc >> 7;               // 0..31
    int slt = Cc & 127;
    int gsl = (slt & ~7) | ((slt ^ row) & 7);
    short8 v = *(const short8*)&Ui[(size_t)(c0 + row) * 1024 + gsl * 8];
    *(short8*)&Ui_s[row * 1024 + slt * 8] = v;
  }

  // Uf fragments -> registers (layout matches MFMA B-operand; no swizzle needed)
  short8 bF[2][16];
#pragma unroll
  for (int ct = 0; ct < 2; ++ct)
#pragma unroll
    for (int c = 0; c < 16; ++c) {
      int kc = kh * 16 + c;
      bF[ct][c] = *(const short8*)&Uf[(size_t)(c0 + ct * 16 + l15) * 1024 + kc * 32 + quad * 8];
    }

  float hreg[8] = {};                 // fp32 h master (kh0 only), [ct*4+r]
  float nxe[8] = {};                  // xe inputs (kh0, prefetched regs)
  if (kh == 0) {
    // prologue pf for t=0: xf/xi -> pfL[0], xe -> nxe
#pragma unroll
    for (int g = 0; g < 2; ++g)
#pragma unroll
      for (int ct = 0; ct < 2; ++ct)
#pragma unroll
        for (int r = 0; r < 4; ++r) {
          const float* src = xfi + (size_t)(rw + quad * 4 + r) * 2048 + g * 1024 + c0 + ct * 16 + l15;
          gld_lds4(src, (void*)&pfL[0][w3][g][ct][r][0]);
        }
#pragma unroll
    for (int ct = 0; ct < 2; ++ct)
#pragma unroll
      for (int r = 0; r < 4; ++r)
        nxe[ct * 4 + r] = bf2f(xe16[(size_t)(rw + quad * 4 + r) * 1024 + c0 + ct * 16 + l15]);
  }
  __syncthreads();   // Ui staged, pfL[0] complete (syncthreads drains vmcnt)

  const char* hbase = (const char*)h16;
  const size_t aoff =
      ((size_t)(rw + l15) * 256 + (size_t)kh * 128 + (size_t)quad * 2) * 8;  // bytes

#define GLD(dst, off_)                                                       \
  asm volatile("global_load_dwordx4 %0, %1, off offset:" off_ " sc0 sc1"     \
               : "=&v"(dst) : "v"(ab) : "memory")
#define CONSUME(c, Avar)                                                     \
  {                                                                          \
    const int slin = (kh * 16 + (c)) * 4 + quad;                             \
    const int slt = (slin & ~7) | ((slin ^ l15) & 7);                        \
    short8 a = __builtin_bit_cast(short8, Avar);                             \
    short8 bi0 = *(const short8*)&Ui_s[l15 * 1024 + slt * 8];                \
    short8 bi1 = *(const short8*)&Ui_s[(16 + l15) * 1024 + slt * 8];         \
    aF0 = MFMA16(a, bF[0][(c)], aF0);                                        \
    aF1 = MFMA16(a, bF[1][(c)], aF1);                                        \
    aI0 = MFMA16(a, bi0, aI0);                                               \
    aI1 = MFMA16(a, bi1, aI1);                                               \
  }

  for (int t = 0; t < 512; ++t) {
    const int rp = t & 1;
    f32x4 aF0 = {0.f, 0.f, 0.f, 0.f}, aF1 = aF0, aI0 = aF0, aI1 = aF0;
    if (t > 0) {
      // ---- throttled poll of the 32 producer blocks ----
      {
        const unsigned* fp = flg + (lane & 31);
        unsigned v = AT_LOAD_U32(fp);
        while (!__all((int)(v >= (unsigned)t))) {
          __builtin_amdgcn_s_sleep(1);
          v = AT_LOAD_U32(fp);
        }
        asm volatile("" ::: "memory");
        __builtin_amdgcn_sched_barrier(0);
      }
      // ---- A-tile: 16x dwordx4 coherent loads (16 rows x k-half), one round-trip ----
      const char* ab = hbase + (size_t)rp * 131072 + aoff;
      u32x4 A0, A1, A2, A3, A4, A5, A6, A7, A8, A9, A10, A11, A12, A13, A14, A15;
      GLD(A0, "0");    GLD(A1, "64");   GLD(A2, "128");  GLD(A3, "192");
      GLD(A4, "256");  GLD(A5, "320");  GLD(A6, "384");  GLD(A7, "448");
      GLD(A8, "512");  GLD(A9, "576");  GLD(A10, "640"); GLD(A11, "704");
      GLD(A12, "768"); GLD(A13, "832"); GLD(A14, "896"); GLD(A15, "960");
      asm volatile("s_waitcnt vmcnt(8)" ::: "memory");
      __builtin_amdgcn_sched_barrier(0);
      CONSUME(0, A0) CONSUME(1, A1) CONSUME(2, A2) CONSUME(3, A3)
      CONSUME(4, A4) CONSUME(5, A5) CONSUME(6, A6) CONSUME(7, A7)
      asm volatile("s_waitcnt vmcnt(0)" ::: "memory");
      __builtin_amdgcn_sched_barrier(0);
      CONSUME(8, A8)   CONSUME(9, A9)   CONSUME(10, A10) CONSUME(11, A11)
      CONSUME(12, A12) CONSUME(13, A13) CONSUME(14, A14) CONSUME(15, A15)
    }
    // k-half 1 publishes partials to LDS (single buffer; safe via barriers #1/#2)
    if (kh == 1) {
#pragma unroll
      for (int r = 0; r < 4; ++r) {
        Pr[w3][0][0][r][lane] = aF0[r];
        Pr[w3][0][1][r][lane] = aF1[r];
        Pr[w3][1][0][r][lane] = aI0[r];
        Pr[w3][1][1][r][lane] = aI1[r];
      }
    }
    __syncthreads();   // barrier #1: partials visible (no vmem outstanding here)
    if (kh == 0) {
      unsigned short hb[8];
#pragma unroll
      for (int ct = 0; ct < 2; ++ct)
#pragma unroll
        for (int r = 0; r < 4; ++r) {
          float sf = (ct ? aF1[r] : aF0[r]) + Pr[w3][0][ct][r][lane];
          float si = (ct ? aI1[r] : aI0[r]) + Pr[w3][1][ct][r][lane];
          float xf = pfL[rp][w3][0][ct][r][lane];
          float xi = pfL[rp][w3][1][ct][r][lane];
          float fg = sigmoidf_(xf + sf);
          float ig = sigmoidf_(xi + si);
          float hn = fg * hreg[ct * 4 + r] + ig * nxe[ct * 4 + r];
          hreg[ct * 4 + r] = hn;
          hb[ct * 4 + r] = f2bf(hn);
        }
      // publish h as coherent 32-bit stores: lane-xor pairs adjacent columns (4 stores)
      {
        unsigned* hwp = (unsigned*)(h16 + (size_t)(rp ^ 1) * 65536);
#pragma unroll
        for (int ct = 0; ct < 2; ++ct) {
          unsigned p01 = hb[ct * 4 + 0] | ((unsigned)hb[ct * 4 + 1] << 16);
          unsigned p23 = hb[ct * 4 + 2] | ((unsigned)hb[ct * 4 + 3] << 16);
          unsigned q01 = (unsigned)__shfl_xor((int)p01, 1, 64);
          unsigned q23 = (unsigned)__shfl_xor((int)p23, 1, 64);
          const int cph = (c0 + ct * 16 + (l15 & ~1)) >> 1;   // dword col index
          const int rbase = rw + quad * 4;
          if (!(l15 & 1)) {
            unsigned dw0 = (p01 & 0xffffu) | (q01 << 16);
            unsigned dw1 = (p01 >> 16) | (q01 & 0xffff0000u);
            AT_STORE_U32(hwp + (size_t)(rbase + 0) * 512 + cph, dw0);
            AT_STORE_U32(hwp + (size_t)(rbase + 1) * 512 + cph, dw1);
          } else {
            unsigned dw2 = (q23 & 0xffffu) | (p23 << 16);
            unsigned dw3 = (q23 >> 16) | (p23 & 0xffff0000u);
            AT_STORE_U32(hwp + (size_t)(rbase + 2) * 512 + cph, dw2);
            AT_STORE_U32(hwp + (size_t)(rbase + 3) * 512 + cph, dw3);
          }
        }
      }
      if (t < 511) {
        __builtin_amdgcn_sched_barrier(0);   // stores stay OLDEST in vmcnt order
        // pf for t+1: 16x gld_lds (xf/xi -> pfL[rp^1]) + 8x xe -> regs = 24 vmem ops
        const size_t mb = (size_t)(t + 1) * 64;
        const int par2 = rp ^ 1;
#pragma unroll
        for (int g = 0; g < 2; ++g)
#pragma unroll
          for (int ct = 0; ct < 2; ++ct)
#pragma unroll
            for (int r = 0; r < 4; ++r) {
              const float* src =
                  xfi + (mb + rw + quad * 4 + r) * 2048 + g * 1024 + c0 + ct * 16 + l15;
              gld_lds4(src, (void*)&pfL[par2][w3][g][ct][r][0]);
            }
#pragma unroll
        for (int ct = 0; ct < 2; ++ct)
#pragma unroll
          for (int r = 0; r < 4; ++r)
            nxe[ct * 4 + r] =
                bf2f(xe16[(mb + rw + quad * 4 + r) * 1024 + c0 + ct * 16 + l15]);
        __builtin_amdgcn_sched_barrier(0);
        // counted ack: 4 stores (oldest) done; 24 pf remain in flight across barrier #2
        asm volatile("s_waitcnt vmcnt(24)" ::: "memory");
      }
    }
    if (t < 511) {
      __builtin_amdgcn_sched_barrier(0);
      __builtin_amdgcn_s_barrier();          // barrier #2 RAW: no vmcnt drain
      __builtin_amdgcn_sched_barrier(0);
      if (tid == 0) AT_STORE_U32(flg + blockIdx.x, (unsigned)(t + 1));
    }
  }
#undef GLD
#undef CONSUME
  // t=511 wrote buffer 0. fc_kernel launch's implicit acquire makes it visible.
}

// ---------------- final FC: out[b][c] = h @ fc_w^T + fc_b (c < 1000) ----------------
__global__ __launch_bounds__(256) void fc_kernel(const short* __restrict__ h16,
                                                 const short* __restrict__ fcw16,
                                                 const float* __restrict__ fcb,
                                                 float* __restrict__ out) {
  const int tid = threadIdx.x;
  const int wave = tid >> 6, lane = tid & 63;
  const int quad = lane >> 4, l15 = lane & 15;
  const int c = blockIdx.x * 64 + wave * 16 + l15;
  f32x4 acc[4] = {};
#pragma unroll
  for (int kc = 0; kc < 32; ++kc) {
    int k = kc * 32 + quad * 8;
    short8 b = *(const short8*)&fcw16[(size_t)c * 1024 + k];
#pragma unroll
    for (int i = 0; i < 4; ++i) {
      short8 a = *(const short8*)&h16[(size_t)(i * 16 + l15) * 1024 + k];
      acc[i] = MFMA16(a, b, acc[i]);
    }
  }
  if (c < 1000) {
    float bias = fcb[c];
#pragma unroll
    for (int i = 0; i < 4; ++i)
#pragma unroll
      for (int r = 0; r < 4; ++r) {
        int m = i * 16 + quad * 4 + r;
        out[m * 1000 + c] = acc[i][r] + bias;
      }
  }
}

extern "C" void kernel_launch(void* const* d_in, const int* in_sizes, int n_in,
                              void* d_out, int out_size, void* d_ws, size_t ws_size,
                              hipStream_t stream) {
  const int* x = (const int*)d_in[0];
  const float* emb = (const float*)d_in[1];
  const float* Wf_w = (const float*)d_in[2];
  const float* Wf_b = (const float*)d_in[3];
  const float* Uf_w = (const float*)d_in[4];
  const float* Wi_w = (const float*)d_in[5];
  const float* Wi_b = (const float*)d_in[6];
  const float* Ui_w = (const float*)d_in[7];
  const float* fc_w = (const float*)d_in[8];
  const float* fc_b = (const float*)d_in[9];
  float* out = (float*)d_out;

  char* ws = (char*)d_ws;
  size_t off = 0;
  auto alloc = [&](size_t bytes) {
    char* p = ws + off;
    off += (bytes + 255) & ~(size_t)255;
    return p;
  };
  short* xe16 = (short*)alloc((size_t)SB_ROWS * 1024 * 2);       // 64 MB
  float* xfi  = (float*)alloc((size_t)SB_ROWS * 2048 * 4);       // 256 MB
  short* Wf16 = (short*)alloc(1024ull * 1024 * 2);
  short* Wi16 = (short*)alloc(1024ull * 1024 * 2);
  short* Uf16 = (short*)alloc(1024ull * 1024 * 2);
  short* Ui16 = (short*)alloc(1024ull * 1024 * 2);
  short* fcw16 = (short*)alloc(1024ull * 1024 * 2);
  short* h16 = (short*)alloc(2ull * 65536 * 2);                  // ping-pong bf16 h
  unsigned* flg = (unsigned*)alloc(256 * sizeof(unsigned));      // per-block step flags
  if (off > ws_size) return;

  hipMemsetAsync((void*)flg, 0, 256 * sizeof(unsigned), stream);
  cast_bf16_k<<<1024, 256, 0, stream>>>(Wf_w, Wf16, 1024 * 1024);
  cast_bf16_k<<<1024, 256, 0, stream>>>(Wi_w, Wi16, 1024 * 1024);
  cast_bf16_k<<<1024, 256, 0, stream>>>(Uf_w, Uf16, 1024 * 1024);
  cast_bf16_k<<<1024, 256, 0, stream>>>(Ui_w, Ui16, 1024 * 1024);
  cast_bf16_k<<<1000, 256, 0, stream>>>(fc_w, fcw16, 1000 * 1024);
  embed_gather<<<SB_ROWS, 128, 0, stream>>>(x, emb, xe16);
  gemm_xfi<<<(SB_ROWS / 128) * 16, 256, 0, stream>>>(xe16, Wf16, Wi16, Wf_b, Wi_b, xfi);

  const float* xfi_a = xfi;
  const short* xe_a = xe16;
  const short* uf_a = Uf16;
  const short* ui_a = Ui16;
  short* h16_a = h16;
  unsigned* flg_a = flg;
  void* args[] = {(void*)&xfi_a, (void*)&xe_a, (void*)&uf_a,
                  (void*)&ui_a,  (void*)&h16_a, (void*)&flg_a};
  (void)hipLaunchCooperativeKernel((void*)ran_scan, dim3(32), dim3(512), args, 0, stream);

  // after t=511 (odd): final h is in buffer 0
  fc_kernel<<<16, 256, 0, stream>>>(h16, fcw16, fc_b, out);
}

// Round 6
// 2673.729 us; speedup vs baseline: 1.7062x; 1.7062x over previous
//
#include <hip/hip_runtime.h>
#include <hip/hip_cooperative_groups.h>

typedef __attribute__((ext_vector_type(8))) short short8;   // 8 bf16 (4 VGPRs)
typedef __attribute__((ext_vector_type(4))) float f32x4;
typedef __attribute__((ext_vector_type(4))) float floatx4;
typedef __attribute__((ext_vector_type(4))) unsigned int uintx4;
typedef __attribute__((ext_vector_type(2))) unsigned int uintx2;
typedef __attribute__((ext_vector_type(4))) unsigned int u32x4;

#define MFMA16(a, b, c) __builtin_amdgcn_mfma_f32_16x16x32_bf16(a, b, c, 0, 0, 0)

// B=64, S=512, V=32000, D=1024, H=1024, C=1000
#define SB_ROWS 32768   // S*B, row m = s*64 + b

#define AT_LOAD_U32(p)  __hip_atomic_load((p), __ATOMIC_RELAXED, __HIP_MEMORY_SCOPE_AGENT)
#define AT_STORE_U32(p, v) __hip_atomic_store((p), (v), __ATOMIC_RELAXED, __HIP_MEMORY_SCOPE_AGENT)

__device__ __forceinline__ unsigned short f2bf(float f) {
  unsigned u = __float_as_uint(f);
  u += 0x7fffu + ((u >> 16) & 1u);          // RNE
  return (unsigned short)(u >> 16);
}
__device__ __forceinline__ float bf2f(short s) {
  return __uint_as_float(((unsigned)(unsigned short)s) << 16);
}
__device__ __forceinline__ float sigmoidf_(float x) {
  return 1.0f / (1.0f + __expf(-x));
}
__device__ __forceinline__ void gld_lds16(const void* g, void* l) {
  __builtin_amdgcn_global_load_lds(
      (const __attribute__((address_space(1))) unsigned int*)g,
      (__attribute__((address_space(3))) unsigned int*)l, 16, 0, 0);
}

// ---------------- f32 -> bf16 cast (n multiple of 4) ----------------
__global__ __launch_bounds__(256) void cast_bf16_k(const float* __restrict__ src,
                                                   short* __restrict__ dst, int n) {
  int i = (blockIdx.x * 256 + threadIdx.x) * 4;
  if (i >= n) return;
  floatx4 v = *(const floatx4*)(src + i);
  unsigned int lo = f2bf(v.x) | ((unsigned)f2bf(v.y) << 16);
  unsigned int hi = f2bf(v.z) | ((unsigned)f2bf(v.w) << 16);
  uintx2 o; o.x = lo; o.y = hi;
  *(uintx2*)(dst + i) = o;
}

// ---------------- embedding gather: xe16[s*64+b][d] = bf16(emb[x[b][s]][d]) ----------------
__global__ __launch_bounds__(128) void embed_gather(const int* __restrict__ x,
                                                    const float* __restrict__ emb,
                                                    short* __restrict__ xe16) {
  const int m = blockIdx.x;            // s*64 + b
  const int s = m >> 6, b = m & 63;
  const int idx = x[b * 512 + s];
  const int d0 = threadIdx.x * 8;
  const float* src = emb + (size_t)idx * 1024 + d0;
  floatx4 a = *(const floatx4*)src;
  floatx4 c = *(const floatx4*)(src + 4);
  uintx4 o;
  o.x = f2bf(a.x) | ((unsigned)f2bf(a.y) << 16);
  o.y = f2bf(a.z) | ((unsigned)f2bf(a.w) << 16);
  o.z = f2bf(c.x) | ((unsigned)f2bf(c.y) << 16);
  o.w = f2bf(c.z) | ((unsigned)f2bf(c.w) << 16);
  *(uintx4*)(xe16 + (size_t)m * 1024 + d0) = o;
}

// ---------------- batched projections: xfi[m][0:1024]=xe@Wf^T+bf, [1024:2048]=xe@Wi^T+bi ----
__global__ __launch_bounds__(256, 2) void gemm_xfi(const short* __restrict__ A,
                                                   const short* __restrict__ Wf,
                                                   const short* __restrict__ Wi,
                                                   const float* __restrict__ bfp,
                                                   const float* __restrict__ bip,
                                                   float* __restrict__ Cout) {
  __shared__ __align__(16) short As[128 * 64];
  __shared__ __align__(16) short Bs[128 * 64];
  const int tid = threadIdx.x;
  const int wave = tid >> 6, lane = tid & 63;
  const int quad = lane >> 4, l15 = lane & 15;
  const int nt = blockIdx.x & 15;
  const long m0 = (long)(blockIdx.x >> 4) * 128;
  const int n0 = nt * 128;
  const short* Bm = (n0 < 1024) ? Wf : Wi;
  const int nb = (n0 < 1024) ? n0 : n0 - 1024;
  const int wm = (wave >> 1) * 64, wn = (wave & 1) * 64;

  f32x4 acc[4][4] = {};
  const int cb = wave * 4;

  for (int k0 = 0; k0 < 1024; k0 += 64) {
    __syncthreads();
#pragma unroll
    for (int q = 0; q < 4; ++q) {
      int Cc = (cb + q) * 64 + lane;
      int row = Cc >> 3, slot = Cc & 7;
      int gk = k0 + ((slot ^ (row & 7)) << 3);
      gld_lds16(A + (m0 + row) * 1024 + gk, As + (size_t)(cb + q) * 512);
      gld_lds16(Bm + (long)(nb + row) * 1024 + gk, Bs + (size_t)(cb + q) * 512);
    }
    __syncthreads();
#pragma unroll
    for (int ks = 0; ks < 2; ++ks) {
      short8 av[4], bv[4];
      const int slin = ks * 4 + quad;
#pragma unroll
      for (int i = 0; i < 4; ++i) {
        int row = wm + i * 16 + l15;
        int slot = slin ^ (row & 7);
        av[i] = *(const short8*)&As[row * 64 + slot * 8];
      }
#pragma unroll
      for (int j = 0; j < 4; ++j) {
        int col = wn + j * 16 + l15;
        int slot = slin ^ (col & 7);
        bv[j] = *(const short8*)&Bs[col * 64 + slot * 8];
      }
#pragma unroll
      for (int i = 0; i < 4; ++i)
#pragma unroll
        for (int j = 0; j < 4; ++j) acc[i][j] = MFMA16(av[i], bv[j], acc[i][j]);
    }
  }
#pragma unroll
  for (int j = 0; j < 4; ++j) {
    int ng = n0 + wn + j * 16 + l15;
    float bias = (ng < 1024) ? bfp[ng] : bip[ng - 1024];
#pragma unroll
    for (int i = 0; i < 4; ++i)
#pragma unroll
      for (int r = 0; r < 4; ++r) {
        long m = m0 + wm + i * 16 + quad * 4 + r;
        Cout[m * 2048 + ng] = acc[i][j][r] + bias;
      }
  }
}

// ---------------- cooperative recurrence: 512 steps, 64 blocks x 512 thr ----------------
// R9 (resubmit; R5 run was an infra failure): exploit ROW-INDEPENDENCE of the recurrence.
// Grid = 4 rowgroups x 16 colslices. Block (ri,cj): rows ri*16..+16, cols cj*64..+64.
//  - Coherent h-read per block = 16 rows x 1024 k = 32 KB/step (was 128 KB): staged
//    DISJOINTLY by the 8 waves into LDS (XOR-swizzled), shared via ds_read. 4x less
//    per-CU coherent-load pipe time and 4x less LLC service.
//  - 4 rowgroups are fully independent pipelines; poll = 16 flags of own rowgroup only.
//  - Waves = 4 coltiles x 2 gates. Each wave: 1 rowtile x 1 coltile x 32 ksteps x 1 gate
//    = 32 MFMA, U-fragments live ENTIRELY in registers (32 x short8 = 128 VGPR; legal:
//    launch_bounds(512,1) -> 256 VGPR budget). No cross-wave k-reduce; only a 4 KB
//    i-gate -> f-gate exchange in LDS.
//  - Per-step: poll -> stage (4x dwordx4 sc0 sc1, 1 RT) -> barA -> 32 ds_read+MFMA ->
//    exch -> barB -> gate -> 2 paired dword stores -> pf(t+1) -> vmcnt(12) (acks stores,
//    pf stays in flight) -> raw s_barrier -> tid0 flag.
// Cross-block safety: block writes rows(ri) x cols(cj) of buffer rp^1 at t only after
// poll(t) proves all 16 blocks of rowgroup ri finished reading that buffer at t-1.
__global__ __launch_bounds__(512, 1) void ran_scan(const float* __restrict__ xfi,
                                                   const short* __restrict__ xe16,
                                                   const short* __restrict__ Uf,
                                                   const short* __restrict__ Ui,
                                                   short* __restrict__ h16,
                                                   unsigned* __restrict__ flg) {
  __shared__ __align__(16) short h_s[16 * 1024];     // 32 KB staged A-rows (swizzled)
  __shared__ float exch[4][4][64];                   // 4 KB i-gate partials
  const int tid = threadIdx.x;
  const int wave = tid >> 6, lane = tid & 63;
  const int ct = wave >> 1, g = wave & 1;            // coltile, gate
  const int quad = lane >> 4, l15 = lane & 15;
  const int ri = blockIdx.x >> 4, cj = blockIdx.x & 15;
  const int rowbase = ri * 16;                       // batch rows
  const int colbase = cj * 64 + ct * 16;             // h cols of this wave

  // U fragments -> registers (B-operand layout: col=l15, k=s*32+quad*8)
  short8 bU[32];
  {
    const short* U = g ? Ui : Uf;
#pragma unroll
    for (int s = 0; s < 32; ++s)
      bU[s] = *(const short8*)&U[(size_t)(colbase + l15) * 1024 + s * 32 + quad * 8];
  }

  float hreg[4] = {};                 // fp32 h master (f-waves), rows rowbase+quad*4+r
  float xfc[4], xic[4], xec[4];       // current-step inputs (f-waves)
  if (g == 0) {
#pragma unroll
    for (int r = 0; r < 4; ++r) {
      int m = rowbase + quad * 4 + r;                // t=0 rows
      xfc[r] = xfi[(size_t)m * 2048 + colbase + l15];
      xic[r] = xfi[(size_t)m * 2048 + 1024 + colbase + l15];
      xec[r] = bf2f(xe16[(size_t)m * 1024 + colbase + l15]);
    }
  }

  char* hs_b = (char*)h_s;
  const char* hbase = (const char*)h16;
  // stage: wave w loads k-chunks w*16..+16 for rows rowbase..+16 (4 KB, disjoint)
  // load j covers rows quad+4j, chunk16 = l15 (of the wave's 16 chunks)
  const size_t stage_off =
      (size_t)(rowbase + quad) * 2048 + (size_t)wave * 256 + (size_t)l15 * 16;

#define GLDP(dst, p)                                                         \
  asm volatile("global_load_dwordx4 %0, %1, off sc0 sc1"                     \
               : "=&v"(dst) : "v"(p) : "memory")

  for (int t = 0; t < 512; ++t) {
    const int rp = t & 1;
    f32x4 a0 = {0.f, 0.f, 0.f, 0.f}, a1 = a0;
    if (t > 0) {
      // ---- poll the 16 producer blocks of my rowgroup ----
      {
        const unsigned* fp = flg + (ri * 16 + (lane & 15));
        unsigned v = AT_LOAD_U32(fp);
        while (!__all((int)(v >= (unsigned)t))) {
          __builtin_amdgcn_s_sleep(1);
          v = AT_LOAD_U32(fp);
        }
        asm volatile("" ::: "memory");
        __builtin_amdgcn_sched_barrier(0);
      }
      // ---- stage my 4 KB slice of h rows: 4 coherent dwordx4, one RT ----
      const char* ab = hbase + (size_t)rp * 131072 + stage_off;
      u32x4 S0, S1, S2, S3;
      GLDP(S0, ab);
      GLDP(S1, ab + 8192);
      GLDP(S2, ab + 16384);
      GLDP(S3, ab + 24576);
      asm volatile("s_waitcnt vmcnt(0)" ::: "memory");
      __builtin_amdgcn_sched_barrier(0);
      // swizzled LDS writes: chunk kc = wave*16 + l15, row = j*4 + quad
#pragma unroll
      for (int j = 0; j < 4; ++j) {
        const int row = j * 4 + quad;
        const int kc = wave * 16 + l15;
        u32x4 S = (j == 0) ? S0 : (j == 1) ? S1 : (j == 2) ? S2 : S3;
        *(short8*)&hs_b[row * 2048 + ((kc ^ (row & 7)) << 4)] =
            __builtin_bit_cast(short8, S);
      }
    }
    __syncthreads();   // barrier A: h_s staged (t=0: h=0, skip compute)
    if (t > 0) {
#pragma unroll
      for (int s = 0; s < 32; ++s) {
        short8 a = *(const short8*)
            &hs_b[l15 * 2048 + (((s * 4 + quad) ^ (l15 & 7)) << 4)];
        if (s & 1) a1 = MFMA16(a, bU[s], a1);
        else       a0 = MFMA16(a, bU[s], a0);
      }
    }
    if (g == 1) {
#pragma unroll
      for (int r = 0; r < 4; ++r) exch[ct][r][lane] = a0[r] + a1[r];
    }
    __syncthreads();   // barrier B: i-gate partials visible
    if (g == 0) {
      unsigned short hb[4];
#pragma unroll
      for (int r = 0; r < 4; ++r) {
        float sf = a0[r] + a1[r];
        float si = exch[ct][r][lane];
        float fg = sigmoidf_(xfc[r] + sf);
        float ig = sigmoidf_(xic[r] + si);
        float hn = fg * hreg[r] + ig * xec[r];
        hreg[r] = hn;
        hb[r] = f2bf(hn);
      }
      // paired coherent stores: lane-xor makes dwords of adjacent columns
      {
        unsigned* hwp = (unsigned*)(h16 + (size_t)(rp ^ 1) * 65536);
        unsigned p01 = hb[0] | ((unsigned)hb[1] << 16);
        unsigned p23 = hb[2] | ((unsigned)hb[3] << 16);
        unsigned q01 = (unsigned)__shfl_xor((int)p01, 1, 64);
        unsigned q23 = (unsigned)__shfl_xor((int)p23, 1, 64);
        const int cph = (colbase + (l15 & ~1)) >> 1;   // dword col index
        const int rbase = rowbase + quad * 4;
        if (!(l15 & 1)) {
          unsigned dw0 = (p01 & 0xffffu) | (q01 << 16);
          unsigned dw1 = (p01 >> 16) | (q01 & 0xffff0000u);
          AT_STORE_U32(hwp + (size_t)(rbase + 0) * 512 + cph, dw0);
          AT_STORE_U32(hwp + (size_t)(rbase + 1) * 512 + cph, dw1);
        } else {
          unsigned dw2 = (q23 & 0xffffu) | (p23 << 16);
          unsigned dw3 = (q23 >> 16) | (p23 & 0xffff0000u);
          AT_STORE_U32(hwp + (size_t)(rbase + 2) * 512 + cph, dw2);
          AT_STORE_U32(hwp + (size_t)(rbase + 3) * 512 + cph, dw3);
        }
      }
      if (t < 511) {
        __builtin_amdgcn_sched_barrier(0);   // stores stay OLDEST in vmcnt order
        // pf t+1 inputs (12 HBM loads; latency hides under next poll+stage)
        const size_t mb = (size_t)(t + 1) * 64;
#pragma unroll
        for (int r = 0; r < 4; ++r) {
          size_t m = mb + rowbase + quad * 4 + r;
          xfc[r] = xfi[m * 2048 + colbase + l15];
          xic[r] = xfi[m * 2048 + 1024 + colbase + l15];
          xec[r] = bf2f(xe16[m * 1024 + colbase + l15]);
        }
        __builtin_amdgcn_sched_barrier(0);
        // counted ack: 2 stores (oldest) done; 12 pf loads remain in flight
        asm volatile("s_waitcnt vmcnt(12)" ::: "memory");
        __builtin_amdgcn_sched_barrier(0);
      }
    }
    if (t < 511) {
      __builtin_amdgcn_s_barrier();          // barrier C RAW: no vmcnt drain
      if (tid == 0) AT_STORE_U32(flg + blockIdx.x, (unsigned)(t + 1));
    }
  }
#undef GLDP
  // t=511 wrote buffer 0. fc_kernel launch's implicit acquire makes it visible.
}

// ---------------- final FC: out[b][c] = h @ fc_w^T + fc_b (c < 1000) ----------------
__global__ __launch_bounds__(256) void fc_kernel(const short* __restrict__ h16,
                                                 const short* __restrict__ fcw16,
                                                 const float* __restrict__ fcb,
                                                 float* __restrict__ out) {
  const int tid = threadIdx.x;
  const int wave = tid >> 6, lane = tid & 63;
  const int quad = lane >> 4, l15 = lane & 15;
  const int c = blockIdx.x * 64 + wave * 16 + l15;
  f32x4 acc[4] = {};
#pragma unroll
  for (int kc = 0; kc < 32; ++kc) {
    int k = kc * 32 + quad * 8;
    short8 b = *(const short8*)&fcw16[(size_t)c * 1024 + k];
#pragma unroll
    for (int i = 0; i < 4; ++i) {
      short8 a = *(const short8*)&h16[(size_t)(i * 16 + l15) * 1024 + k];
      acc[i] = MFMA16(a, b, acc[i]);
    }
  }
  if (c < 1000) {
    float bias = fcb[c];
#pragma unroll
    for (int i = 0; i < 4; ++i)
#pragma unroll
      for (int r = 0; r < 4; ++r) {
        int m = i * 16 + quad * 4 + r;
        out[m * 1000 + c] = acc[i][r] + bias;
      }
  }
}

extern "C" void kernel_launch(void* const* d_in, const int* in_sizes, int n_in,
                              void* d_out, int out_size, void* d_ws, size_t ws_size,
                              hipStream_t stream) {
  const int* x = (const int*)d_in[0];
  const float* emb = (const float*)d_in[1];
  const float* Wf_w = (const float*)d_in[2];
  const float* Wf_b = (const float*)d_in[3];
  const float* Uf_w = (const float*)d_in[4];
  const float* Wi_w = (const float*)d_in[5];
  const float* Wi_b = (const float*)d_in[6];
  const float* Ui_w = (const float*)d_in[7];
  const float* fc_w = (const float*)d_in[8];
  const float* fc_b = (const float*)d_in[9];
  float* out = (float*)d_out;

  char* ws = (char*)d_ws;
  size_t off = 0;
  auto alloc = [&](size_t bytes) {
    char* p = ws + off;
    off += (bytes + 255) & ~(size_t)255;
    return p;
  };
  short* xe16 = (short*)alloc((size_t)SB_ROWS * 1024 * 2);       // 64 MB
  float* xfi  = (float*)alloc((size_t)SB_ROWS * 2048 * 4);       // 256 MB
  short* Wf16 = (short*)alloc(1024ull * 1024 * 2);
  short* Wi16 = (short*)alloc(1024ull * 1024 * 2);
  short* Uf16 = (short*)alloc(1024ull * 1024 * 2);
  short* Ui16 = (short*)alloc(1024ull * 1024 * 2);
  short* fcw16 = (short*)alloc(1024ull * 1024 * 2);
  short* h16 = (short*)alloc(2ull * 65536 * 2);                  // ping-pong bf16 h
  unsigned* flg = (unsigned*)alloc(256 * sizeof(unsigned));      // per-block step flags
  if (off > ws_size) return;

  hipMemsetAsync((void*)flg, 0, 256 * sizeof(unsigned), stream);
  cast_bf16_k<<<1024, 256, 0, stream>>>(Wf_w, Wf16, 1024 * 1024);
  cast_bf16_k<<<1024, 256, 0, stream>>>(Wi_w, Wi16, 1024 * 1024);
  cast_bf16_k<<<1024, 256, 0, stream>>>(Uf_w, Uf16, 1024 * 1024);
  cast_bf16_k<<<1024, 256, 0, stream>>>(Ui_w, Ui16, 1024 * 1024);
  cast_bf16_k<<<1000, 256, 0, stream>>>(fc_w, fcw16, 1000 * 1024);
  embed_gather<<<SB_ROWS, 128, 0, stream>>>(x, emb, xe16);
  gemm_xfi<<<(SB_ROWS / 128) * 16, 256, 0, stream>>>(xe16, Wf16, Wi16, Wf_b, Wi_b, xfi);

  const float* xfi_a = xfi;
  const short* xe_a = xe16;
  const short* uf_a = Uf16;
  const short* ui_a = Ui16;
  short* h16_a = h16;
  unsigned* flg_a = flg;
  void* args[] = {(void*)&xfi_a, (void*)&xe_a, (void*)&uf_a,
                  (void*)&ui_a,  (void*)&h16_a, (void*)&flg_a};
  (void)hipLaunchCooperativeKernel((void*)ran_scan, dim3(64), dim3(512), args, 0, stream);

  // after t=511 (odd): final h is in buffer 0
  fc_kernel<<<16, 256, 0, stream>>>(h16, fcw16, fc_b, out);
}